// Round 3
// baseline (701912.012 us; speedup 1.0000x reference)
//
#include <hip/hip_runtime.h>
#include <hip/hip_fp16.h>

#define B_ 256
#define S_ 512
#define F_ 64
#define H_ 1024
#define O_ 24
#define G_ 4096  // 4*H

typedef _Float16 half_t;
typedef _Float16 h8 __attribute__((ext_vector_type(8)));
typedef float f4 __attribute__((ext_vector_type(4)));

// ---- workspace layout (bytes) ----
#define OFF_H1 ((size_t)0)                                   // 2*B*H halfs (ping-pong)
#define OFF_H2 (OFF_H1 + (size_t)2*B_*H_*2)
#define OFF_C1 (OFF_H2 + (size_t)2*B_*H_*2)                  // B*H f32
#define OFF_C2 (OFF_C1 + (size_t)B_*H_*4)
#define OFF_OP (OFF_C2 + (size_t)B_*H_*4)                    // out_part [32][B][O] f32
#define ZBYTES (OFF_OP + (size_t)32*B_*O_*4)
#define OFF_BIAS0 (ZBYTES)
#define OFF_BIAS1 (OFF_BIAS0 + (size_t)G_*4)
#define OFF_XH    (OFF_BIAS1 + (size_t)G_*4)                 // B*S*F halfs
#define OFF_WIH0  (OFF_XH + (size_t)B_*S_*F_*2)              // G*F halfs
#define OFF_WHH0  (OFF_WIH0 + (size_t)G_*F_*2)               // G*H halfs
#define OFF_WIH1  (OFF_WHH0 + (size_t)G_*H_*2)
#define OFF_WHH1  (OFF_WIH1 + (size_t)G_*H_*2)
#define WS_NEEDED (OFF_WHH1 + (size_t)G_*H_*2)               // ~47.5 MB

__global__ void k_bias(const float* __restrict__ bi0, const float* __restrict__ bh0,
                       const float* __restrict__ bi1, const float* __restrict__ bh1,
                       float* __restrict__ bias0, float* __restrict__ bias1) {
    int i = blockIdx.x * blockDim.x + threadIdx.x;
    if (i < G_) { bias0[i] = bi0[i] + bh0[i]; bias1[i] = bi1[i] + bh1[i]; }
}

__global__ void k_cvt(const float* __restrict__ src, half_t* __restrict__ dst, int n) {
    int i = blockIdx.x * blockDim.x + threadIdx.x;
    int stride = gridDim.x * blockDim.x;
    for (; i < n; i += stride) dst[i] = (half_t)src[i];
}

// Fused phase kernel: phase t = layer0 step t (blocks 256..511) + layer1 step
// t-1 (blocks 0..255), 2 blocks/CU. Block tile 32b x 32h x 4 gates, wave=gate.
// W fragments are loaded DIRECTLY global->VGPR (no LDS round-trip: zero
// cross-wave reuse for W, and weights are L2-resident via the ht%8==XCD map).
// Only A (shared by all 4 waves) is staged through LDS.
__global__ __launch_bounds__(256, 2)
void k_phase(int t,
             const half_t* __restrict__ x_h,
             const half_t* __restrict__ Wih0, const half_t* __restrict__ Whh0,
             const float* __restrict__ bias0, float* __restrict__ c1, half_t* __restrict__ h1buf,
             const half_t* __restrict__ Wih1, const half_t* __restrict__ Whh1,
             const float* __restrict__ bias1, float* __restrict__ c2, half_t* __restrict__ h2buf,
             const float* __restrict__ fcW, float* __restrict__ out_part)
{
    // LDS: A staging unioned with gate-exchange (epilogue after final barrier)
    __shared__ __align__(16) char smraw[23040];
    half_t* A_s    = (half_t*)smraw;                     // 32 x 72
    float*  gate_s = (float*)smraw;                      // [4][32*33]
    float*  h_s    = (float*)(smraw + 4 * 32 * 33 * 4);  // [32*33]

    const int n  = blockIdx.x;
    const bool l1 = (n < 256);
    const int m  = l1 ? n : n - 256;
    const int ht = (m & 7) + 8 * ((m >> 3) & 3);   // ht % 8 == linear_id % 8 (XCD-resident W)
    const int bt = (m >> 5) & 7;

    int tt; const half_t* xb; int ldx, cx; const half_t* Wih; int ldwih;
    const half_t* Whh; const float* bias; float* c; half_t* hn_out; const half_t* hp;
    if (l1) {
        if (t == 0) return;
        tt = t - 1;
        xb  = h1buf + (size_t)(tt & 1) * B_ * H_;  ldx = H_;      cx = 16;
        Wih = Wih1;  ldwih = H_;  Whh = Whh1;  bias = bias1;  c = c2;
        hp     = h2buf + (size_t)((tt - 1) & 1) * B_ * H_;
        hn_out = h2buf + (size_t)(tt & 1) * B_ * H_;
    } else {
        if (t >= S_) return;
        tt = t;
        xb  = x_h + (size_t)tt * F_;  ldx = S_ * F_;  cx = 1;
        Wih = Wih0;  ldwih = F_;  Whh = Whh0;  bias = bias0;  c = c1;
        hp     = h1buf + (size_t)((tt - 1) & 1) * B_ * H_;
        hn_out = h1buf + (size_t)(tt & 1) * B_ * H_;
    }

    const int thr  = threadIdx.x;
    const int wave = thr >> 6, lane = thr & 63;
    const int quad = lane >> 4, l15 = lane & 15;
    const int hbase = ht * 32;

    // bias folded into accumulator init (col = nt*16 + l15)
    float bv0 = bias[wave * H_ + hbase + l15];
    float bv1 = bias[wave * H_ + hbase + 16 + l15];
    f4 acc[2][2];
    #pragma unroll
    for (int mt = 0; mt < 2; ++mt) {
        acc[mt][0] = (f4){bv0, bv0, bv0, bv0};
        acc[mt][1] = (f4){bv1, bv1, bv1, bv1};
    }

    const int nchunks = cx + 16;            // K = cx*64 + 1024
    const int ar = thr >> 3;                // A staging row 0..31
    const int ak = (thr & 7) * 8;           // A staging k-offset

    // W fragment rows for this wave (B-operand of gates = A @ W^T):
    // frag col-half 0: rows gate*H + hbase + l15; col-half 1: +16. k = k0 + ks + quad*8.
    const int wrow0 = wave * H_ + hbase + l15;
    const int wrow1 = wrow0 + 16;

    f4 pA;             // A prefetch (staging slot, not fragment)
    h8 wbuf[2][4];     // W fragment double buffer: [ck&1][colhalf*2 + ks]

    auto fetchA = [&](int ck) {
        const half_t* Ab; int lda, k0;
        if (ck < cx) { Ab = xb; lda = ldx; k0 = ck * 64; }
        else         { Ab = hp; lda = H_;  k0 = (ck - cx) * 64; }
        pA = *(const f4*)&Ab[(size_t)(bt * 32 + ar) * lda + k0 + ak];
    };
    auto fetchW = [&](int ck) {
        const half_t* Wb; int ldw, k0;
        if (ck < cx) { Wb = Wih; ldw = ldwih; k0 = ck * 64; }
        else         { Wb = Whh; ldw = H_;    k0 = (ck - cx) * 64; }
        const int kq = k0 + quad * 8;
        h8* dst = wbuf[ck & 1];
        dst[0] = *(const h8*)&Wb[(size_t)wrow0 * ldw + kq];
        dst[1] = *(const h8*)&Wb[(size_t)wrow0 * ldw + kq + 32];
        dst[2] = *(const h8*)&Wb[(size_t)wrow1 * ldw + kq];
        dst[3] = *(const h8*)&Wb[(size_t)wrow1 * ldw + kq + 32];
    };

    fetchA(0);
    fetchW(0);
    for (int ck = 0; ck < nchunks; ++ck) {
        *(f4*)&A_s[ar * 72 + ak] = pA;
        __syncthreads();
        if (ck + 1 < nchunks) { fetchA(ck + 1); fetchW(ck + 1); }  // fly during MFMA

        const h8* w = wbuf[ck & 1];
        #pragma unroll
        for (int ks = 0; ks < 64; ks += 32) {
            h8 a0 = *(const h8*)&A_s[(0  + l15) * 72 + ks + quad * 8];
            h8 a1 = *(const h8*)&A_s[(16 + l15) * 72 + ks + quad * 8];
            h8 b0 = w[(ks >> 5)];
            h8 b1 = w[2 + (ks >> 5)];
            acc[0][0] = __builtin_amdgcn_mfma_f32_16x16x32_f16(a0, b0, acc[0][0], 0, 0, 0);
            acc[0][1] = __builtin_amdgcn_mfma_f32_16x16x32_f16(a0, b1, acc[0][1], 0, 0, 0);
            acc[1][0] = __builtin_amdgcn_mfma_f32_16x16x32_f16(a1, b0, acc[1][0], 0, 0, 0);
            acc[1][1] = __builtin_amdgcn_mfma_f32_16x16x32_f16(a1, b1, acc[1][1], 0, 0, 0);
        }
        __syncthreads();
    }

    // scatter gates (C/D layout col=lane&15, row=quad*4+reg)
    #pragma unroll
    for (int mt = 0; mt < 2; ++mt)
        #pragma unroll
        for (int nt = 0; nt < 2; ++nt)
            #pragma unroll
            for (int r = 0; r < 4; ++r)
                gate_s[wave * (32 * 33) + (mt * 16 + quad * 4 + r) * 33 + nt * 16 + l15] = acc[mt][nt][r];
    __syncthreads();

    // cell update: 1024 (b,h) elems, 4/thread
    #pragma unroll
    for (int kk = 0; kk < 4; ++kk) {
        int e = thr + kk * 256;
        int b = e >> 5, col = e & 31;
        float gi = gate_s[0 * (32 * 33) + b * 33 + col];
        float gf = gate_s[1 * (32 * 33) + b * 33 + col];
        float gg = gate_s[2 * (32 * 33) + b * 33 + col];
        float go = gate_s[3 * (32 * 33) + b * 33 + col];
        float si = 1.f / (1.f + __expf(-gi));
        float sf = 1.f / (1.f + __expf(-gf));
        float so = 1.f / (1.f + __expf(-go));
        float tg = tanhf(gg);
        size_t cidx = (size_t)(bt * 32 + b) * H_ + hbase + col;
        float cn = sf * c[cidx] + si * tg;
        c[cidx] = cn;
        float hnv = so * tanhf(cn);
        hn_out[cidx] = (half_t)hnv;
        h_s[b * 33 + col] = hnv;
    }

    if (l1) {
        __syncthreads();
        const float* fcWt = fcW + (size_t)tt * H_;
        for (int p = thr; p < 32 * O_; p += 256) {
            int o = p >> 5, bb = p & 31;
            float s = 0.f;
            #pragma unroll 8
            for (int j = 0; j < 32; ++j)
                s += h_s[bb * 33 + j] * fcWt[(size_t)o * (S_ * H_) + hbase + j];
            out_part[ht * (B_ * O_) + (bt * 32 + bb) * O_ + o] += s;
        }
    }
}

__global__ void k_final(const float* __restrict__ out_part, const float* __restrict__ fcb,
                        float* __restrict__ out) {
    int i = blockIdx.x * blockDim.x + threadIdx.x;
    if (i >= B_ * O_) return;
    int o = i % O_;
    float s = fcb[o];
    for (int t = 0; t < 32; ++t) s += out_part[t * (B_ * O_) + i];
    out[i] = s;
}

extern "C" void kernel_launch(void* const* d_in, const int* in_sizes, int n_in,
                              void* d_out, int out_size, void* d_ws, size_t ws_size,
                              hipStream_t stream) {
    const float* x    = (const float*)d_in[0];
    const float* Wih0 = (const float*)d_in[1];
    const float* Whh0 = (const float*)d_in[2];
    const float* bih0 = (const float*)d_in[3];
    const float* bhh0 = (const float*)d_in[4];
    const float* Wih1 = (const float*)d_in[5];
    const float* Whh1 = (const float*)d_in[6];
    const float* bih1 = (const float*)d_in[7];
    const float* bhh1 = (const float*)d_in[8];
    const float* fcW  = (const float*)d_in[9];
    const float* fcb  = (const float*)d_in[10];

    char* ws = (char*)d_ws;
    half_t* h1buf  = (half_t*)(ws + OFF_H1);
    half_t* h2buf  = (half_t*)(ws + OFF_H2);
    float*  c1     = (float*)(ws + OFF_C1);
    float*  c2     = (float*)(ws + OFF_C2);
    float*  opart  = (float*)(ws + OFF_OP);
    float*  bias0  = (float*)(ws + OFF_BIAS0);
    float*  bias1  = (float*)(ws + OFF_BIAS1);
    half_t* x_h    = (half_t*)(ws + OFF_XH);
    half_t* wih0_h = (half_t*)(ws + OFF_WIH0);
    half_t* whh0_h = (half_t*)(ws + OFF_WHH0);
    half_t* wih1_h = (half_t*)(ws + OFF_WIH1);
    half_t* whh1_h = (half_t*)(ws + OFF_WHH1);

    // zero states + FC partials (ws is poisoned 0xAA before every launch)
    hipMemsetAsync(d_ws, 0, ZBYTES, stream);

    k_bias<<<dim3((G_ + 255) / 256), dim3(256), 0, stream>>>(bih0, bhh0, bih1, bhh1, bias0, bias1);
    k_cvt<<<dim3(2048), dim3(256), 0, stream>>>(x,    x_h,    B_ * S_ * F_);
    k_cvt<<<dim3(256),  dim3(256), 0, stream>>>(Wih0, wih0_h, G_ * F_);
    k_cvt<<<dim3(2048), dim3(256), 0, stream>>>(Whh0, whh0_h, G_ * H_);
    k_cvt<<<dim3(2048), dim3(256), 0, stream>>>(Wih1, wih1_h, G_ * H_);
    k_cvt<<<dim3(2048), dim3(256), 0, stream>>>(Whh1, whh1_h, G_ * H_);

    dim3 grid(512), blk(256);
    for (int t = 0; t <= S_; ++t) {
        k_phase<<<grid, blk, 0, stream>>>(t, x_h,
                                          wih0_h, whh0_h, bias0, c1, h1buf,
                                          wih1_h, whh1_h, bias1, c2, h2buf,
                                          fcW, opart);
    }
    k_final<<<dim3((B_ * O_ + 255) / 256), dim3(256), 0, stream>>>(opart, fcb, (float*)d_out);
}

// Round 4
// 11571.016 us; speedup vs baseline: 60.6612x; 60.6612x over previous
//
#include <hip/hip_runtime.h>
#include <hip/hip_fp16.h>

#define B_ 256
#define S_ 512
#define F_ 64
#define H_ 1024
#define O_ 24
#define G_ 4096  // 4*H

typedef _Float16 half_t;
typedef _Float16 h8 __attribute__((ext_vector_type(8)));
typedef float f4 __attribute__((ext_vector_type(4)));

// ---- workspace layout (bytes) ----
#define OFF_H1 ((size_t)0)                                   // 2*B*H halfs (ping-pong)
#define OFF_H2 (OFF_H1 + (size_t)2*B_*H_*2)
#define OFF_C1 (OFF_H2 + (size_t)2*B_*H_*2)                  // B*H f32
#define OFF_C2 (OFF_C1 + (size_t)B_*H_*4)
#define OFF_OP (OFF_C2 + (size_t)B_*H_*4)                    // out_part [32][B][O] f32
#define ZBYTES (OFF_OP + (size_t)32*B_*O_*4)
#define OFF_BIAS0 (ZBYTES)
#define OFF_BIAS1 (OFF_BIAS0 + (size_t)G_*4)
#define OFF_XH    (OFF_BIAS1 + (size_t)G_*4)                 // B*S*F halfs
#define OFF_WIH0  (OFF_XH + (size_t)B_*S_*F_*2)              // packed, G*F halfs
#define OFF_WHH0  (OFF_WIH0 + (size_t)G_*F_*2)               // packed, G*H halfs
#define OFF_WIH1  (OFF_WHH0 + (size_t)G_*H_*2)
#define OFF_WHH1  (OFF_WIH1 + (size_t)G_*H_*2)
#define WS_NEEDED (OFF_WHH1 + (size_t)G_*H_*2)               // ~47.5 MB

__global__ void k_bias(const float* __restrict__ bi0, const float* __restrict__ bh0,
                       const float* __restrict__ bi1, const float* __restrict__ bh1,
                       float* __restrict__ bias0, float* __restrict__ bias1) {
    int i = blockIdx.x * blockDim.x + threadIdx.x;
    if (i < G_) { bias0[i] = bi0[i] + bh0[i]; bias1[i] = bi1[i] + bh1[i]; }
}

__global__ void k_cvt(const float* __restrict__ src, half_t* __restrict__ dst, int n) {
    int i = blockIdx.x * blockDim.x + threadIdx.x;
    int stride = gridDim.x * blockDim.x;
    for (; i < n; i += stride) dst[i] = (half_t)src[i];
}

// Pack W [4H, NC*64] f32 -> fp16 MFMA-fragment order:
// dst h8 index i = (((g*32+ht)*NC + ck)*4 + j)*64 + lane, j = colhalf*2 + kshalf
// source row = g*H + ht*32 + (j>>1)*16 + (lane&15)
// source col = ck*64 + (j&1)*32 + (lane>>4)*8 + e
__global__ void k_pack(const float* __restrict__ src, half_t* __restrict__ dst, int NC) {
    int i = blockIdx.x * blockDim.x + threadIdx.x;
    int total = 32768 * NC;          // 4*32*NC*4*64
    if (i >= total) return;
    int lane = i & 63;
    int j    = (i >> 6) & 3;
    int ck   = (i >> 8) % NC;
    int gh   = i / (256 * NC);       // g*32+ht, 0..127
    int srow = (gh >> 5) * H_ + (gh & 31) * 32 + (j >> 1) * 16 + (lane & 15);
    int scol = ck * 64 + (j & 1) * 32 + (lane >> 4) * 8;
    const float* s = src + (size_t)srow * (NC * 64) + scol;
    h8 v;
    #pragma unroll
    for (int e = 0; e < 8; ++e) v[e] = (half_t)s[e];
    *(h8*)&dst[(size_t)i * 8] = v;
}

// Fused phase kernel: phase t = layer0 step t (blocks 256..511) + layer1 step
// t-1 (blocks 0..255), 2 blocks/CU. Block tile 32b x 32h x 4 gates, wave=gate.
// W fragments load DIRECTLY global->VGPR from the packed (fragment-order)
// arrays: 1 coalesced 1KB dwordx4 per wave-instruction, L2-resident via the
// ht%8==XCD map. Only A (4x cross-wave reuse) goes through LDS.
// Double-buffer uses NAMED registers (never a runtime-indexed local array —
// that allocates to scratch and was a 55x regression in round 2).
__global__ __launch_bounds__(256, 2)
void k_phase(int t,
             const half_t* __restrict__ x_h,
             const half_t* __restrict__ Wih0, const half_t* __restrict__ Whh0,
             const float* __restrict__ bias0, float* __restrict__ c1, half_t* __restrict__ h1buf,
             const half_t* __restrict__ Wih1, const half_t* __restrict__ Whh1,
             const float* __restrict__ bias1, float* __restrict__ c2, half_t* __restrict__ h2buf,
             const float* __restrict__ fcW, float* __restrict__ out_part)
{
    __shared__ __align__(16) char smraw[23040];
    half_t* A_s    = (half_t*)smraw;                     // 32 x 72
    float*  gate_s = (float*)smraw;                      // [4][32*33] (after final barrier)
    float*  h_s    = (float*)(smraw + 4 * 32 * 33 * 4);  // [32*33]

    const int n  = blockIdx.x;
    const bool l1 = (n < 256);
    const int m  = l1 ? n : n - 256;
    const int ht = (m & 7) + 8 * ((m >> 3) & 3);   // ht % 8 == linear_id % 8 (XCD-resident W)
    const int bt = (m >> 5) & 7;

    int tt; const half_t* xb; int ldx, cx; const half_t* Wih;
    const half_t* Whh; const float* bias; float* c; half_t* hn_out; const half_t* hp;
    if (l1) {
        if (t == 0) return;
        tt = t - 1;
        xb  = h1buf + (size_t)(tt & 1) * B_ * H_;  ldx = H_;      cx = 16;
        Wih = Wih1;  Whh = Whh1;  bias = bias1;  c = c2;
        hp     = h2buf + (size_t)((tt - 1) & 1) * B_ * H_;
        hn_out = h2buf + (size_t)(tt & 1) * B_ * H_;
    } else {
        if (t >= S_) return;
        tt = t;
        xb  = x_h + (size_t)tt * F_;  ldx = S_ * F_;  cx = 1;
        Wih = Wih0;  Whh = Whh0;  bias = bias0;  c = c1;
        hp     = h1buf + (size_t)((tt - 1) & 1) * B_ * H_;
        hn_out = h1buf + (size_t)(tt & 1) * B_ * H_;
    }

    const int thr  = threadIdx.x;
    const int wave = thr >> 6, lane = thr & 63;
    const int quad = lane >> 4, l15 = lane & 15;
    const int hbase = ht * 32;

    // bias folded into accumulator init (col = nt*16 + l15)
    float bv0 = bias[wave * H_ + hbase + l15];
    float bv1 = bias[wave * H_ + hbase + 16 + l15];
    f4 acc[2][2];
    #pragma unroll
    for (int mt = 0; mt < 2; ++mt) {
        acc[mt][0] = (f4){bv0, bv0, bv0, bv0};
        acc[mt][1] = (f4){bv1, bv1, bv1, bv1};
    }

    const int nchunks = cx + 16;            // K = cx*64 + 1024
    const int ar = thr >> 3;                // A staging row 0..31
    const int ak = (thr & 7) * 8;           // A staging k-offset

    // packed-W base for this wave's (gate, ht): h8 group index (((wave*32+ht)*NC+ck)*4+j)*64+lane
    const int ghW = wave * 32 + ht;

    f4 pA;
    h8 c0, c1r, c2r, c3;   // current W fragments (j = 0..3)
    h8 n0, n1, n2, n3;     // next

    auto fetchA = [&](int ck) {
        const half_t* Ab; int lda, k0;
        if (ck < cx) { Ab = xb; lda = ldx; k0 = ck * 64; }
        else         { Ab = hp; lda = H_;  k0 = (ck - cx) * 64; }
        pA = *(const f4*)&Ab[(size_t)(bt * 32 + ar) * lda + k0 + ak];
    };
    auto fetchW = [&](int ck, h8& r0, h8& r1, h8& r2, h8& r3) {
        const half_t* Wb; int ckk, NC;
        if (ck < cx) { Wb = Wih; ckk = ck;      NC = cx; }
        else         { Wb = Whh; ckk = ck - cx; NC = 16; }
        const half_t* base = Wb + ((size_t)(((ghW * NC) + ckk) * 4) * 64 + lane) * 8;
        r0 = *(const h8*)(base + 0 * 512);
        r1 = *(const h8*)(base + 1 * 512);
        r2 = *(const h8*)(base + 2 * 512);
        r3 = *(const h8*)(base + 3 * 512);
    };

    fetchA(0);
    fetchW(0, c0, c1r, c2r, c3);
    for (int ck = 0; ck < nchunks; ++ck) {
        *(f4*)&A_s[ar * 72 + ak] = pA;
        __syncthreads();
        if (ck + 1 < nchunks) { fetchA(ck + 1); fetchW(ck + 1, n0, n1, n2, n3); }

        // ks = 0: b0 = j0 (ch0,ks0), b1 = j2 (ch1,ks0)
        h8 a0 = *(const h8*)&A_s[(0  + l15) * 72 + 0 + quad * 8];
        h8 a1 = *(const h8*)&A_s[(16 + l15) * 72 + 0 + quad * 8];
        acc[0][0] = __builtin_amdgcn_mfma_f32_16x16x32_f16(a0, c0,  acc[0][0], 0, 0, 0);
        acc[0][1] = __builtin_amdgcn_mfma_f32_16x16x32_f16(a0, c2r, acc[0][1], 0, 0, 0);
        acc[1][0] = __builtin_amdgcn_mfma_f32_16x16x32_f16(a1, c0,  acc[1][0], 0, 0, 0);
        acc[1][1] = __builtin_amdgcn_mfma_f32_16x16x32_f16(a1, c2r, acc[1][1], 0, 0, 0);
        // ks = 32: b0 = j1 (ch0,ks1), b1 = j3 (ch1,ks1)
        h8 a2 = *(const h8*)&A_s[(0  + l15) * 72 + 32 + quad * 8];
        h8 a3 = *(const h8*)&A_s[(16 + l15) * 72 + 32 + quad * 8];
        acc[0][0] = __builtin_amdgcn_mfma_f32_16x16x32_f16(a2, c1r, acc[0][0], 0, 0, 0);
        acc[0][1] = __builtin_amdgcn_mfma_f32_16x16x32_f16(a2, c3,  acc[0][1], 0, 0, 0);
        acc[1][0] = __builtin_amdgcn_mfma_f32_16x16x32_f16(a3, c1r, acc[1][0], 0, 0, 0);
        acc[1][1] = __builtin_amdgcn_mfma_f32_16x16x32_f16(a3, c3,  acc[1][1], 0, 0, 0);
        __syncthreads();

        c0 = n0; c1r = n1; c2r = n2; c3 = n3;
    }

    // scatter gates (C/D layout col=lane&15, row=quad*4+reg)
    #pragma unroll
    for (int mt = 0; mt < 2; ++mt)
        #pragma unroll
        for (int nt = 0; nt < 2; ++nt)
            #pragma unroll
            for (int r = 0; r < 4; ++r)
                gate_s[wave * (32 * 33) + (mt * 16 + quad * 4 + r) * 33 + nt * 16 + l15] = acc[mt][nt][r];
    __syncthreads();

    // cell update: 1024 (b,h) elems, 4/thread
    #pragma unroll
    for (int kk = 0; kk < 4; ++kk) {
        int e = thr + kk * 256;
        int b = e >> 5, col = e & 31;
        float gi = gate_s[0 * (32 * 33) + b * 33 + col];
        float gf = gate_s[1 * (32 * 33) + b * 33 + col];
        float gg = gate_s[2 * (32 * 33) + b * 33 + col];
        float go = gate_s[3 * (32 * 33) + b * 33 + col];
        float si = 1.f / (1.f + __expf(-gi));
        float sf = 1.f / (1.f + __expf(-gf));
        float so = 1.f / (1.f + __expf(-go));
        float tg = tanhf(gg);
        size_t cidx = (size_t)(bt * 32 + b) * H_ + hbase + col;
        float cn = sf * c[cidx] + si * tg;
        c[cidx] = cn;
        float hnv = so * tanhf(cn);
        hn_out[cidx] = (half_t)hnv;
        h_s[b * 33 + col] = hnv;
    }

    if (l1) {
        __syncthreads();
        const float* fcWt = fcW + (size_t)tt * H_;
        for (int p = thr; p < 32 * O_; p += 256) {
            int o = p >> 5, bb = p & 31;
            float s = 0.f;
            #pragma unroll 8
            for (int j = 0; j < 32; ++j)
                s += h_s[bb * 33 + j] * fcWt[(size_t)o * (S_ * H_) + hbase + j];
            out_part[ht * (B_ * O_) + (bt * 32 + bb) * O_ + o] += s;
        }
    }
}

__global__ void k_final(const float* __restrict__ out_part, const float* __restrict__ fcb,
                        float* __restrict__ out) {
    int i = blockIdx.x * blockDim.x + threadIdx.x;
    if (i >= B_ * O_) return;
    int o = i % O_;
    float s = fcb[o];
    for (int t = 0; t < 32; ++t) s += out_part[t * (B_ * O_) + i];
    out[i] = s;
}

extern "C" void kernel_launch(void* const* d_in, const int* in_sizes, int n_in,
                              void* d_out, int out_size, void* d_ws, size_t ws_size,
                              hipStream_t stream) {
    const float* x    = (const float*)d_in[0];
    const float* Wih0 = (const float*)d_in[1];
    const float* Whh0 = (const float*)d_in[2];
    const float* bih0 = (const float*)d_in[3];
    const float* bhh0 = (const float*)d_in[4];
    const float* Wih1 = (const float*)d_in[5];
    const float* Whh1 = (const float*)d_in[6];
    const float* bih1 = (const float*)d_in[7];
    const float* bhh1 = (const float*)d_in[8];
    const float* fcW  = (const float*)d_in[9];
    const float* fcb  = (const float*)d_in[10];

    char* ws = (char*)d_ws;
    half_t* h1buf  = (half_t*)(ws + OFF_H1);
    half_t* h2buf  = (half_t*)(ws + OFF_H2);
    float*  c1     = (float*)(ws + OFF_C1);
    float*  c2     = (float*)(ws + OFF_C2);
    float*  opart  = (float*)(ws + OFF_OP);
    float*  bias0  = (float*)(ws + OFF_BIAS0);
    float*  bias1  = (float*)(ws + OFF_BIAS1);
    half_t* x_h    = (half_t*)(ws + OFF_XH);
    half_t* wih0_p = (half_t*)(ws + OFF_WIH0);
    half_t* whh0_p = (half_t*)(ws + OFF_WHH0);
    half_t* wih1_p = (half_t*)(ws + OFF_WIH1);
    half_t* whh1_p = (half_t*)(ws + OFF_WHH1);

    hipMemsetAsync(d_ws, 0, ZBYTES, stream);

    k_bias<<<dim3((G_ + 255) / 256), dim3(256), 0, stream>>>(bih0, bhh0, bih1, bhh1, bias0, bias1);
    k_cvt<<<dim3(2048), dim3(256), 0, stream>>>(x, x_h, B_ * S_ * F_);
    k_pack<<<dim3(128),  dim3(256), 0, stream>>>(Wih0, wih0_p, 1);
    k_pack<<<dim3(2048), dim3(256), 0, stream>>>(Whh0, whh0_p, 16);
    k_pack<<<dim3(2048), dim3(256), 0, stream>>>(Wih1, wih1_p, 16);
    k_pack<<<dim3(2048), dim3(256), 0, stream>>>(Whh1, whh1_p, 16);

    dim3 grid(512), blk(256);
    for (int t = 0; t <= S_; ++t) {
        k_phase<<<grid, blk, 0, stream>>>(t, x_h,
                                          wih0_p, whh0_p, bias0, c1, h1buf,
                                          wih1_p, whh1_p, bias1, c2, h2buf,
                                          fcW, opart);
    }
    k_final<<<dim3((B_ * O_ + 255) / 256), dim3(256), 0, stream>>>(opart, fcb, (float*)d_out);
}